// Round 26
// baseline (917.880 us; speedup 1.0000x reference)
//
#include <hip/hip_runtime.h>
#include <hip/hip_bf16.h>

typedef unsigned long long ull;

// ---------------- problem constants ----------------
constexpr int BATCH = 8;
constexpr int NA    = 261888;
constexpr int KSEL  = 6000;          // PRE_NMS_LIMIT
constexpr int PROP  = 1000;          // PROPOSAL_COUNT
constexpr int CAP   = 8192;          // candidate capacity
constexpr int NBINS = 8192;          // histogram bins
constexpr int HB    = 16;            // private histogram blocks per batch
constexpr int NB    = (KSEL + 63) / 64;   // 94 words per row
constexpr int NBLK  = 94;            // row-blocks

// workspace layout (bytes). keys/hist alias the old mask region (now scratch).
constexpr size_t OFF_CNT   = 0;                       // 512 (128 ints)
constexpr size_t OFF_TSEL  = 512;                     // 32
constexpr size_t OFF_BOXES = 544;                     // 8*6000*16 = 768000
constexpr size_t OFF_MASK  = 769024;                  // scratch region (ex-mask)
constexpr size_t OFF_DIAG  = OFF_MASK + 36096000;     // 8*94*64*8 = 385024
constexpr size_t OFF_SUP   = OFF_DIAG + 385024;       // 8*94*64*8 = 385024
constexpr size_t OFF_KEYS  = OFF_MASK;                // 524288 (aliased scratch)
constexpr size_t OFF_HIST  = OFF_MASK + 2097152;      // 4MB (aliased scratch)
// total = 37,635,072 B

__device__ __forceinline__ int score_bin(float s) {
  int b = (int)(s * (float)NBINS);
  if (b < 0) b = 0;
  if (b > NBINS - 1) b = NBINS - 1;
  return b;
}

// exact IoU>0.7 test, bit-identical to reference rounding (proven formula)
__device__ __forceinline__ bool iou_keep(const float4& rb, float rA,
                                         const float4& cb, float cA) {
  float ih = fmaxf(fminf(rb.z, cb.z) - fmaxf(rb.x, cb.x), 0.f);
  float iw = fmaxf(fminf(rb.w, cb.w) - fmaxf(rb.y, cb.y), 0.f);
  float inter = ih * iw;
  float uni = (rA + cA) - inter;
  float d = fmaf(-0.7f, uni, inter);
  float tt = 6e-7f * uni;
  if (__builtin_fabsf(d) <= tt) return (inter / uni) > 0.7f; // rare tie; 0/0->NaN->false
  return d > 0.f;
}

// ---------------- 1. histogram (+ init: cnt zero, keys 0xFF pad) ----------------
__global__ __launch_bounds__(256) void hist_kernel(const float2* __restrict__ probs,
                                                   unsigned int* __restrict__ hist,
                                                   int* __restrict__ cnt,
                                                   ull* __restrict__ keys) {
  __shared__ unsigned int lh[NBINS];
  for (int i = threadIdx.x; i < NBINS; i += 256) lh[i] = 0u;
  int fb = blockIdx.y * HB + blockIdx.x;   // 0..127
  if (threadIdx.x == 0) cnt[fb] = 0;
  {
    ull* kp = keys + (size_t)fb * 512;
    for (int i = threadIdx.x; i < 512; i += 256) kp[i] = ~0ull;
  }
  __syncthreads();
  int b = blockIdx.y;
  const float2* p = probs + (size_t)b * NA;
  for (int a = blockIdx.x * 256 + threadIdx.x; a < NA; a += HB * 256) {
    atomicAdd(&lh[score_bin(p[a].y)], 1u);
  }
  __syncthreads();
  unsigned int* gh = hist + ((size_t)b * HB + blockIdx.x) * NBINS;
  for (int i = threadIdx.x; i < NBINS; i += 256) gh[i] = lh[i];
}

// ---------------- 2. threshold bin select ----------------
__global__ __launch_bounds__(256) void thresh_kernel(const unsigned int* __restrict__ hist,
                                                     int* __restrict__ tsel) {
  constexpr int GR = NBINS / 256;
  __shared__ unsigned int ch[NBINS];
  __shared__ unsigned int gsum[256];
  int b = blockIdx.x;
  const unsigned int* h = hist + (size_t)b * HB * NBINS;
  for (int bin = threadIdx.x; bin < NBINS; bin += 256) {
    unsigned int s = 0;
    for (int k = 0; k < HB; ++k) s += h[(size_t)k * NBINS + bin];
    ch[bin] = s;
  }
  __syncthreads();
  unsigned int s = 0;
  int g0 = threadIdx.x * GR;
  for (int i = 0; i < GR; ++i) s += ch[g0 + i];
  gsum[threadIdx.x] = s;
  __syncthreads();
  if (threadIdx.x == 0) {
    unsigned int acc = 0;
    int g = 255;
    for (; g > 0; --g) {
      if (acc + gsum[g] >= (unsigned)KSEL) break;
      acc += gsum[g];
    }
    int t = g * GR;
    for (int bin = g * GR + GR - 1; bin >= g * GR; --bin) {
      acc += ch[bin];
      if (acc >= (unsigned)KSEL) { t = bin; break; }
    }
    tsel[b] = t;
  }
}

// ---------------- 3. compact candidates ----------------
__global__ __launch_bounds__(256) void compact_kernel(const float2* __restrict__ probs,
                                                      const int* __restrict__ tsel,
                                                      int* __restrict__ cnt,
                                                      ull* __restrict__ keys) {
  __shared__ int lcnt, lbase;
  __shared__ ull lbuf[2048];
  int b = blockIdx.y;
  int t = tsel[b];
  if (threadIdx.x == 0) lcnt = 0;
  __syncthreads();
  const float2* p = probs + (size_t)b * NA;
  for (int a = blockIdx.x * blockDim.x + threadIdx.x; a < NA; a += gridDim.x * blockDim.x) {
    float s = p[a].y;
    if (score_bin(s) >= t) {
      int pos = atomicAdd(&lcnt, 1);
      unsigned int ib = ~__float_as_uint(s);
      lbuf[pos] = ((ull)ib << 32) | (unsigned int)a;
    }
  }
  __syncthreads();
  if (threadIdx.x == 0) lbase = atomicAdd(&cnt[b * 16], lcnt);
  __syncthreads();
  int n = lcnt, base = lbase;
  ull* kb = keys + (size_t)b * CAP;
  for (int i = threadIdx.x; i < n; i += 256) {
    int pos = base + i;
    if (pos < CAP) kb[pos] = lbuf[i];
  }
}

// ---------------- 4. fused rank+scatter, LDS-tiled key stream ----------------
__global__ __launch_bounds__(256) void rankscatter_kernel(const float4* __restrict__ anchors4,
                                                          const float4* __restrict__ bbox4,
                                                          const int* __restrict__ cnt,
                                                          const ull* __restrict__ keys,
                                                          float4* __restrict__ boxes4) {
#pragma clang fp contract(off)
  __shared__ ull tile[1024];
  int b = blockIdx.y;
  int n = cnt[b * 16];
  if (n > CAP) n = CAP;
  int i = blockIdx.x * 256 + threadIdx.x;
  const ull* kb = keys + (size_t)b * CAP;
  ull my = (i < CAP) ? kb[(i < n) ? i : 0] : ~0ull;
  if (i >= n) my = ~0ull;
  unsigned int r = 0;
  int ntile = (n + 1023) & ~1023;
  for (int j0 = 0; j0 < ntile; j0 += 1024) {
    for (int k = threadIdx.x; k < 1024; k += 256) tile[k] = kb[j0 + k];
    __syncthreads();
#pragma unroll 16
    for (int k = 0; k < 1024; ++k) r += (tile[k] < my) ? 1u : 0u;
    __syncthreads();
  }
  if (i >= n || r >= (unsigned)KSEL) return;
  int a = (int)(unsigned int)(my & 0xffffffffull);
  float4 anc = anchors4[(size_t)b * NA + a];
  float4 d   = bbox4[(size_t)b * NA + a];
  float h = anc.z - anc.x;
  float w = anc.w - anc.y;
  float dy = d.x * 0.1f, dx = d.y * 0.1f, dh = d.z * 0.2f, dw = d.w * 0.2f;
  float cy = (anc.x + (0.5f * h)) + (dy * h);
  float cx = (anc.y + (0.5f * w)) + (dx * w);
  float h2 = h * expf(dh);
  float w2 = w * expf(dw);
  float y1 = cy - 0.5f * h2;
  float x1 = cx - 0.5f * w2;
  float y2 = y1 + h2;
  float x2 = x1 + w2;
  y1 = fminf(fmaxf(y1, 0.f), 1.f);
  x1 = fminf(fmaxf(x1, 0.f), 1.f);
  y2 = fminf(fmaxf(y2, 0.f), 1.f);
  x2 = fminf(fmaxf(x2, 0.f), 1.f);
  boxes4[(size_t)b * KSEL + r] = make_float4(y1, x1, y2, x2);
}

// ---------------- 5. diag+super mini-mask (replaces full mask: 4% of the work) ----------------
// grid (94, 8), 128 thr. wave0: diag tile of block n (col-form via ballot transpose);
// wave1: superdiag tile (word n+1 of block-n rows, row form; zeros at n=93).
__global__ __launch_bounds__(128) void dspmask_kernel(const float4* __restrict__ boxes4,
                                                      ull* __restrict__ diagT,
                                                      ull* __restrict__ superT) {
#pragma clang fp contract(off)
  __shared__ float4 colbox[2][64];
  __shared__ float  colca[2][64];
  int n = blockIdx.x, b = blockIdx.y;
  int tid = threadIdx.x, wv = tid >> 6, l = tid & 63;
  float4 zero = make_float4(0.f, 0.f, 0.f, 0.f);
  int cblk = n + wv;                 // wave0: n, wave1: n+1
  int c = cblk * 64 + l;
  float4 cld = (c < KSEL) ? boxes4[(size_t)b * KSEL + c] : zero;
  colbox[wv][l] = cld;
  colca[wv][l] = (cld.z - cld.x) * (cld.w - cld.y);
  __syncthreads();
  int row = n * 64 + l;
  float4 rb = (row < KSEL) ? boxes4[(size_t)b * KSEL + row] : zero;
  float rA = (rb.z - rb.x) * (rb.w - rb.y);
  ull bits = 0ull;
#pragma unroll
  for (int u = 0; u < 64; ++u) {
    if (iou_keep(rb, rA, colbox[wv][u], colca[wv][u])) bits |= (1ull << u);
  }
  if (wv == 0) {
    bits &= (l == 63) ? 0ull : (~0ull << (l + 1));  // only cc > row suppress
    ull colT = 0ull;
#pragma unroll
    for (int k = 0; k < 64; ++k) {
      ull bk = __ballot(((bits >> k) & 1ull) != 0ull);
      if (l == k) colT = bk;
    }
    diagT[((size_t)b * NBLK + n) * 64 + l] = colT;
  } else {
    superT[((size_t)b * NBLK + n) * 64 + l] = bits;  // word n+1 of block-n rows
  }
}

// ---------------- 6. scan (1024 thr): ballot decision + urgent + lazy ON-THE-FLY IoU ----------------
// wave 0: proven ballot/urgent decision. lanes 64..1023: compute word w of klist[n-1]
// rows directly from boxes (16 lanes/word x 4 cols; row boxes 4-batched; 16-lane
// shfl OR-reduce; single S[w] |= per word). Same completion schedule as the old
// precomputed-mask lazy OR => identical results.
__global__ __launch_bounds__(1024, 1) void scan_kernel(const float4* __restrict__ boxes4,
                                                       const ull* __restrict__ diagT,
                                                       const ull* __restrict__ superT,
                                                       float4* __restrict__ out4) {
#pragma clang fp contract(off)
  __shared__ ull ldiagT[NBLK * 64];  // column form
  __shared__ ull lsuper[NBLK * 64];  // row form
  __shared__ ull S[96];
  __shared__ ull S_urg;
  __shared__ int klist[2][64];
  __shared__ int skeep[1024];
  __shared__ int s_kept, s_done, s_klen[2];
  int b = blockIdx.x;
  int tid = threadIdx.x;
  int lane = tid & 63;
  const float4* bx = boxes4 + (size_t)b * KSEL;
  float4 zero = make_float4(0.f, 0.f, 0.f, 0.f);

  const ull* dt = diagT + (size_t)b * NBLK * 64;
  const ull* st = superT + (size_t)b * NBLK * 64;
  for (int i = tid; i < NBLK * 64; i += 1024) { ldiagT[i] = dt[i]; lsuper[i] = st[i]; }
  if (tid < 96) S[tid] = 0ull;
  if (tid == 0) { s_kept = 0; s_done = 0; s_klen[0] = 0; s_klen[1] = 0; S_urg = 0ull; }
  __syncthreads();

  for (int n = 0; n < NBLK; ++n) {
    if (tid < 64) {
      // ---- wave 0: decision ----
      ull Sn = S[n] | S_urg;
      int i0 = n * 64;
      ull colT = ldiagT[i0 + lane];
      ull sd = (n + 1 < NBLK) ? lsuper[i0 + lane] : 0ull;
      int nval = KSEL - i0;
      ull valid = (nval >= 64) ? ~0ull : ((1ull << nval) - 1ull);
      ull A = ~Sn & valid;
      ull K = 0ull;
      int kept = s_kept;
      int done = 0;
      while (A) {
        int u = __builtin_ctzll(A);
        ++kept;
        K |= (1ull << u);
        if (kept >= PROP) { done = 1; break; }
        ull sup = __ballot(((colT >> u) & 1ull) != 0ull);
        A &= ~(sup | (1ull << u));
      }
      int klen = __builtin_popcountll(K);
      int kbase = kept - klen;
      if ((K >> lane) & 1ull) {
        int rank = __builtin_popcountll(K & ((1ull << lane) - 1ull));
        skeep[kbase + rank] = i0 + lane;
        klist[n & 1][rank] = i0 + lane;
      }
      int klp = (klen + 3) & ~3;     // pad to x4 with a kept-row dup (idempotent)
      if (klen > 0 && lane >= klen && lane < klp)
        klist[n & 1][lane] = i0 + __builtin_ctzll(K);
      unsigned ulo = (unsigned)sd, uhi = (unsigned)(sd >> 32);
      if (!((K >> lane) & 1ull)) { ulo = 0u; uhi = 0u; }
#pragma unroll
      for (int m = 1; m < 64; m <<= 1) {
        ulo |= (unsigned)__shfl_xor((int)ulo, m, 64);
        uhi |= (unsigned)__shfl_xor((int)uhi, m, 64);
      }
      if (lane == 0) {
        s_klen[n & 1] = klen;
        S_urg = (ull)ulo | ((ull)uhi << 32);
        s_kept = kept;
        if (done || n == NBLK - 1) s_done = 1;
      }
    } else {
      // ---- lanes 64..1023: lazy on-the-fly IoU of klist[n-1] vs future words ----
      int prev = (n & 1) ^ 1;
      int kl = s_klen[prev];
      if (kl > 0) {
        int klp4 = (kl + 3) & ~3;
        int lt = tid - 64;           // 0..959
        int wg = lt >> 4;            // 0..59 word-group
        int sub = lt & 15;           // 16 lanes per word
        int c0 = sub * 4;
        int Wcnt = NB - 1 - n;       // words n+1..93
        const int* kp = klist[prev];
        for (int p = 0; p * 60 + wg < Wcnt; ++p) {
          int w = n + 1 + p * 60 + wg;
          float4 cbx0, cbx1, cbx2, cbx3;
          int cc = w * 64 + c0;
          cbx0 = (cc + 0 < KSEL) ? bx[cc + 0] : zero;
          cbx1 = (cc + 1 < KSEL) ? bx[cc + 1] : zero;
          cbx2 = (cc + 2 < KSEL) ? bx[cc + 2] : zero;
          cbx3 = (cc + 3 < KSEL) ? bx[cc + 3] : zero;
          float cA0 = (cbx0.z - cbx0.x) * (cbx0.w - cbx0.y);
          float cA1 = (cbx1.z - cbx1.x) * (cbx1.w - cbx1.y);
          float cA2 = (cbx2.z - cbx2.x) * (cbx2.w - cbx2.y);
          float cA3 = (cbx3.z - cbx3.x) * (cbx3.w - cbx3.y);
          ull bits = 0ull;
          for (int j = 0; j < klp4; j += 4) {
            float4 r0 = bx[kp[j + 0]];
            float4 r1 = bx[kp[j + 1]];
            float4 r2 = bx[kp[j + 2]];
            float4 r3 = bx[kp[j + 3]];
            float a0 = (r0.z - r0.x) * (r0.w - r0.y);
            float a1 = (r1.z - r1.x) * (r1.w - r1.y);
            float a2 = (r2.z - r2.x) * (r2.w - r2.y);
            float a3 = (r3.z - r3.x) * (r3.w - r3.y);
            ull m0 = 0, m1 = 0, m2 = 0, m3 = 0;
            m0 |= (ull)iou_keep(r0, a0, cbx0, cA0) << 0;
            m0 |= (ull)iou_keep(r0, a0, cbx1, cA1) << 1;
            m0 |= (ull)iou_keep(r0, a0, cbx2, cA2) << 2;
            m0 |= (ull)iou_keep(r0, a0, cbx3, cA3) << 3;
            m1 |= (ull)iou_keep(r1, a1, cbx0, cA0) << 0;
            m1 |= (ull)iou_keep(r1, a1, cbx1, cA1) << 1;
            m1 |= (ull)iou_keep(r1, a1, cbx2, cA2) << 2;
            m1 |= (ull)iou_keep(r1, a1, cbx3, cA3) << 3;
            m2 |= (ull)iou_keep(r2, a2, cbx0, cA0) << 0;
            m2 |= (ull)iou_keep(r2, a2, cbx1, cA1) << 1;
            m2 |= (ull)iou_keep(r2, a2, cbx2, cA2) << 2;
            m2 |= (ull)iou_keep(r2, a2, cbx3, cA3) << 3;
            m3 |= (ull)iou_keep(r3, a3, cbx0, cA0) << 0;
            m3 |= (ull)iou_keep(r3, a3, cbx1, cA1) << 1;
            m3 |= (ull)iou_keep(r3, a3, cbx2, cA2) << 2;
            m3 |= (ull)iou_keep(r3, a3, cbx3, cA3) << 3;
            bits |= (m0 | m1) | (m2 | m3);
          }
          bits <<= c0;
          unsigned lo = (unsigned)bits, hi = (unsigned)(bits >> 32);
#pragma unroll
          for (int m = 1; m < 16; m <<= 1) {
            lo |= (unsigned)__shfl_xor((int)lo, m, 64);
            hi |= (unsigned)__shfl_xor((int)hi, m, 64);
          }
          if (sub == 0) S[w] |= (ull)lo | ((ull)hi << 32);
        }
      }
    }
    __syncthreads();
    if (s_done) break;
  }

  int fin = s_kept;
  if (fin > PROP) fin = PROP;
  for (int r2 = tid; r2 < PROP; r2 += 1024) {
    float4 v = make_float4(0.f, 0.f, 0.f, 0.f);
    if (r2 < fin) v = bx[skeep[r2]];
    out4[(size_t)b * PROP + r2] = v;
  }
}

// ---------------- launch (6 dispatches) ----------------
extern "C" void kernel_launch(void* const* d_in, const int* in_sizes, int n_in,
                              void* d_out, int out_size, void* d_ws, size_t ws_size,
                              hipStream_t stream) {
  const float2* probs   = (const float2*)d_in[0];
  const float4* bbox4   = (const float4*)d_in[1];
  const float4* anchors4= (const float4*)d_in[2];
  float4* out4 = (float4*)d_out;
  char* ws = (char*)d_ws;

  int* cnt           = (int*)(ws + OFF_CNT);
  int* tsel          = (int*)(ws + OFF_TSEL);
  float4* boxes4     = (float4*)(ws + OFF_BOXES);
  ull* diagT         = (ull*)(ws + OFF_DIAG);
  ull* superT        = (ull*)(ws + OFF_SUP);
  ull* keys          = (ull*)(ws + OFF_KEYS);
  unsigned int* hist = (unsigned int*)(ws + OFF_HIST);

  hipLaunchKernelGGL(hist_kernel,        dim3(HB, BATCH),    dim3(256),  0, stream, probs, hist, cnt, keys);
  hipLaunchKernelGGL(thresh_kernel,      dim3(BATCH),        dim3(256),  0, stream, hist, tsel);
  hipLaunchKernelGGL(compact_kernel,     dim3(128, BATCH),   dim3(256),  0, stream, probs, tsel, cnt, keys);
  hipLaunchKernelGGL(rankscatter_kernel, dim3(32, BATCH),    dim3(256),  0, stream, anchors4, bbox4, cnt, keys, boxes4);
  hipLaunchKernelGGL(dspmask_kernel,     dim3(NBLK, BATCH),  dim3(128),  0, stream, boxes4, diagT, superT);
  hipLaunchKernelGGL(scan_kernel,        dim3(BATCH),        dim3(1024), 0, stream, boxes4, diagT, superT, out4);
}

// Round 27
// 325.113 us; speedup vs baseline: 2.8233x; 2.8233x over previous
//
#include <hip/hip_runtime.h>
#include <hip/hip_bf16.h>

typedef unsigned long long ull;

// ---------------- problem constants ----------------
constexpr int BATCH = 8;
constexpr int NA    = 261888;
constexpr int KSEL  = 6000;          // PRE_NMS_LIMIT
constexpr int PROP  = 1000;          // PROPOSAL_COUNT
constexpr int CAP   = 8192;          // candidate capacity
constexpr int NBINS = 8192;          // histogram bins
constexpr int HB    = 16;            // private histogram blocks per batch
constexpr int NB    = (KSEL + 63) / 64;   // 94 mask words per row
constexpr int NWP   = 94;            // words per row (752B rows)
constexpr int NBLK  = 94;            // row-blocks
constexpr int NBLK2 = 47;            // 128-row pair-blocks (mask kernel)

// workspace layout (bytes). keys/hist alias the mask head (disjoint liveness).
constexpr size_t OFF_CNT   = 0;                       // 512 (128 ints)
constexpr size_t OFF_TSEL  = 512;                     // 32
constexpr size_t OFF_BOXES = 544;                     // 8*6000*16 = 768000
constexpr size_t OFF_MASK  = 769024;                  // 8*6000*94*8 = 36096000
constexpr size_t OFF_DIAG  = OFF_MASK + 36096000;     // 8*94*64*8 = 385024
constexpr size_t OFF_SUP   = OFF_DIAG + 385024;       // 8*94*64*8 = 385024
constexpr size_t OFF_KEYS  = OFF_MASK;                // 524288 (aliased)
constexpr size_t OFF_HIST  = OFF_MASK + 2097152;      // 4MB (aliased)
// total = 37,635,072 B

__device__ __forceinline__ int score_bin(float s) {
  int b = (int)(s * (float)NBINS);
  if (b < 0) b = 0;
  if (b > NBINS - 1) b = NBINS - 1;
  return b;
}

// ---------------- 1. histogram (+ init: cnt zero, keys 0xFF pad; float4 loads) ----------------
__global__ __launch_bounds__(256) void hist_kernel(const float4* __restrict__ probs4,
                                                   unsigned int* __restrict__ hist,
                                                   int* __restrict__ cnt,
                                                   ull* __restrict__ keys) {
  __shared__ unsigned int lh[NBINS];
  for (int i = threadIdx.x; i < NBINS; i += 256) lh[i] = 0u;
  int fb = blockIdx.y * HB + blockIdx.x;   // 0..127
  if (threadIdx.x == 0) cnt[fb] = 0;
  {
    ull* kp = keys + (size_t)fb * 512;
    for (int i = threadIdx.x; i < 512; i += 256) kp[i] = ~0ull;
  }
  __syncthreads();
  int b = blockIdx.y;
  const float4* p = probs4 + (size_t)b * (NA / 2);
  for (int a = blockIdx.x * 256 + threadIdx.x; a < NA / 2; a += HB * 256) {
    float4 v = p[a];
    atomicAdd(&lh[score_bin(v.y)], 1u);
    atomicAdd(&lh[score_bin(v.w)], 1u);
  }
  __syncthreads();
  unsigned int* gh = hist + ((size_t)b * HB + blockIdx.x) * NBINS;
  for (int i = threadIdx.x; i < NBINS; i += 256) gh[i] = lh[i];
}

// ---------------- 2. threshold bin select ----------------
__global__ __launch_bounds__(256) void thresh_kernel(const unsigned int* __restrict__ hist,
                                                     int* __restrict__ tsel) {
  constexpr int GR = NBINS / 256;
  __shared__ unsigned int ch[NBINS];
  __shared__ unsigned int gsum[256];
  int b = blockIdx.x;
  const unsigned int* h = hist + (size_t)b * HB * NBINS;
  for (int bin = threadIdx.x; bin < NBINS; bin += 256) {
    unsigned int s = 0;
    for (int k = 0; k < HB; ++k) s += h[(size_t)k * NBINS + bin];
    ch[bin] = s;
  }
  __syncthreads();
  unsigned int s = 0;
  int g0 = threadIdx.x * GR;
  for (int i = 0; i < GR; ++i) s += ch[g0 + i];
  gsum[threadIdx.x] = s;
  __syncthreads();
  if (threadIdx.x == 0) {
    unsigned int acc = 0;
    int g = 255;
    for (; g > 0; --g) {
      if (acc + gsum[g] >= (unsigned)KSEL) break;
      acc += gsum[g];
    }
    int t = g * GR;
    for (int bin = g * GR + GR - 1; bin >= g * GR; --bin) {
      acc += ch[bin];
      if (acc >= (unsigned)KSEL) { t = bin; break; }
    }
    tsel[b] = t;
  }
}

// ---------------- 3. compact candidates (float4 loads) ----------------
__global__ __launch_bounds__(256) void compact_kernel(const float4* __restrict__ probs4,
                                                      const int* __restrict__ tsel,
                                                      int* __restrict__ cnt,
                                                      ull* __restrict__ keys) {
  __shared__ int lcnt, lbase;
  __shared__ ull lbuf[2048];
  int b = blockIdx.y;
  int t = tsel[b];
  if (threadIdx.x == 0) lcnt = 0;
  __syncthreads();
  const float4* p = probs4 + (size_t)b * (NA / 2);
  for (int a = blockIdx.x * blockDim.x + threadIdx.x; a < NA / 2; a += gridDim.x * blockDim.x) {
    float4 v = p[a];
    if (score_bin(v.y) >= t) {
      int pos = atomicAdd(&lcnt, 1);
      unsigned int ib = ~__float_as_uint(v.y);
      lbuf[pos] = ((ull)ib << 32) | (unsigned int)(2 * a);
    }
    if (score_bin(v.w) >= t) {
      int pos = atomicAdd(&lcnt, 1);
      unsigned int ib = ~__float_as_uint(v.w);
      lbuf[pos] = ((ull)ib << 32) | (unsigned int)(2 * a + 1);
    }
  }
  __syncthreads();
  if (threadIdx.x == 0) lbase = atomicAdd(&cnt[b * 16], lcnt);
  __syncthreads();
  int n = lcnt, base = lbase;
  ull* kb = keys + (size_t)b * CAP;
  for (int i = threadIdx.x; i < n; i += 256) {
    int pos = base + i;
    if (pos < CAP) kb[pos] = lbuf[i];
  }
}

// ---------------- 4. fused rank+scatter, LDS-tiled key stream (round-25 proven) ----------------
__global__ __launch_bounds__(256) void rankscatter_kernel(const float4* __restrict__ anchors4,
                                                          const float4* __restrict__ bbox4,
                                                          const int* __restrict__ cnt,
                                                          const ull* __restrict__ keys,
                                                          float4* __restrict__ boxes4) {
#pragma clang fp contract(off)
  __shared__ ull tile[1024];
  int b = blockIdx.y;
  int n = cnt[b * 16];
  if (n > CAP) n = CAP;
  int i = blockIdx.x * 256 + threadIdx.x;
  const ull* kb = keys + (size_t)b * CAP;
  ull my = (i < CAP) ? kb[(i < n) ? i : 0] : ~0ull;
  if (i >= n) my = ~0ull;
  unsigned int r = 0;
  int ntile = (n + 1023) & ~1023;
  for (int j0 = 0; j0 < ntile; j0 += 1024) {
    for (int k = threadIdx.x; k < 1024; k += 256) tile[k] = kb[j0 + k];
    __syncthreads();
#pragma unroll 16
    for (int k = 0; k < 1024; ++k) r += (tile[k] < my) ? 1u : 0u;
    __syncthreads();
  }
  if (i >= n || r >= (unsigned)KSEL) return;
  int a = (int)(unsigned int)(my & 0xffffffffull);
  float4 anc = anchors4[(size_t)b * NA + a];
  float4 d   = bbox4[(size_t)b * NA + a];
  float h = anc.z - anc.x;
  float w = anc.w - anc.y;
  float dy = d.x * 0.1f, dx = d.y * 0.1f, dh = d.z * 0.2f, dw = d.w * 0.2f;
  float cy = (anc.x + (0.5f * h)) + (dy * h);
  float cx = (anc.y + (0.5f * w)) + (dx * w);
  float h2 = h * expf(dh);
  float w2 = w * expf(dw);
  float y1 = cy - 0.5f * h2;
  float x1 = cx - 0.5f * w2;
  float y2 = y1 + h2;
  float x2 = x1 + w2;
  y1 = fminf(fmaxf(y1, 0.f), 1.f);
  x1 = fminf(fmaxf(x1, 0.f), 1.f);
  y2 = fminf(fmaxf(y2, 0.f), 1.f);
  x2 = fminf(fmaxf(x2, 0.f), 1.f);
  boxes4[(size_t)b * KSEL + r] = make_float4(y1, x1, y2, x2);
}

// ---------------- 5. suppression mask: 2 rows/thread (round-22/25 proven, 117us) ----------------
__global__ __launch_bounds__(256) void mask_kernel(const float4* __restrict__ boxes4,
                                                   ull* __restrict__ mask,
                                                   ull* __restrict__ diagT,
                                                   ull* __restrict__ superT) {
#pragma clang fp contract(off)
  int cx = blockIdx.x, rb2 = blockIdx.y, b = blockIdx.z;
  int w0 = 2 * rb2;
  int cb0 = w0 + 4 * cx;
  if (cb0 >= NWP) return;
  __shared__ float4 colbox[4][64];
  __shared__ float  colca[4][64];
  __shared__ ull wtile[128][5];
  int tid = threadIdx.x, wv = tid >> 6, l = tid & 63;
  int cb = cb0 + wv;
  int rA = rb2 * 128 + l, rB = rA + 64;
  float4 zero = make_float4(0.f, 0.f, 0.f, 0.f);
  float4 boxA = (rA < KSEL) ? boxes4[(size_t)b * KSEL + rA] : zero;
  float4 boxB = (rB < KSEL) ? boxes4[(size_t)b * KSEL + rB] : zero;
  float areaA = (boxA.z - boxA.x) * (boxA.w - boxA.y);
  float areaB = (boxB.z - boxB.x) * (boxB.w - boxB.y);
  int c = cb * 64 + l;
  float4 cload = (cb < NB && c < KSEL) ? boxes4[(size_t)b * KSEL + c] : zero;
  colbox[wv][l] = cload;
  colca[wv][l] = (cload.z - cload.x) * (cload.w - cload.y);
  __syncthreads();
  ull bitsA = 0ull, bitsB = 0ull;
  if (cb < NB) {
#pragma unroll
    for (int u = 0; u < 64; ++u) {
      float4 cbx = colbox[wv][u];
      float ca = colca[wv][u];
      {
        float ih = fmaxf(fminf(boxA.z, cbx.z) - fmaxf(boxA.x, cbx.x), 0.f);
        float iw = fmaxf(fminf(boxA.w, cbx.w) - fmaxf(boxA.y, cbx.y), 0.f);
        float inter = ih * iw;
        float uni = (areaA + ca) - inter;
        float d = fmaf(-0.7f, uni, inter);
        float tt = 6e-7f * uni;
        bool keep;
        if (__builtin_fabsf(d) <= tt) keep = (inter / uni) > 0.7f;
        else keep = d > 0.f;
        if (keep) bitsA |= (1ull << u);
      }
      {
        float ih = fmaxf(fminf(boxB.z, cbx.z) - fmaxf(boxB.x, cbx.x), 0.f);
        float iw = fmaxf(fminf(boxB.w, cbx.w) - fmaxf(boxB.y, cbx.y), 0.f);
        float inter = ih * iw;
        float uni = (areaB + ca) - inter;
        float d = fmaf(-0.7f, uni, inter);
        float tt = 6e-7f * uni;
        bool keep;
        if (__builtin_fabsf(d) <= tt) keep = (inter / uni) > 0.7f;
        else keep = d > 0.f;
        if (keep) bitsB |= (1ull << u);
      }
    }
    if (cb == w0) {
      bitsA &= (l == 63) ? 0ull : (~0ull << (l + 1)); // only cc > row suppress
      ull colT = 0ull;
#pragma unroll
      for (int k = 0; k < 64; ++k) {
        ull bk = __ballot(((bitsA >> k) & 1ull) != 0ull);
        if (l == k) colT = bk;
      }
      diagT[((size_t)b * NBLK + w0) * 64 + l] = colT;
    }
    if (cb == w0 + 1) {
      superT[((size_t)b * NBLK + w0) * 64 + l] = bitsA;  // word w0+1 of block-w0 rows (row form)
      bitsB &= (l == 63) ? 0ull : (~0ull << (l + 1));
      ull colT = 0ull;
#pragma unroll
      for (int k = 0; k < 64; ++k) {
        ull bk = __ballot(((bitsB >> k) & 1ull) != 0ull);
        if (l == k) colT = bk;
      }
      diagT[((size_t)b * NBLK + w0 + 1) * 64 + l] = colT;
    }
    if (cb == w0 + 2) {
      superT[((size_t)b * NBLK + w0 + 1) * 64 + l] = bitsB; // word w0+2 of block-(w0+1) rows
    }
  }
  wtile[l][wv] = bitsA;
  wtile[l + 64][wv] = bitsB;
  __syncthreads();
  int base_row = rb2 * 128;
#pragma unroll
  for (int pass = 0; pass < 2; ++pass) {
    int idx = pass * 256 + tid;
    int rr = idx >> 2, w = idx & 3;
    int row = base_row + rr;
    if (row < KSEL && cb0 + w < NWP)
      mask[((size_t)b * KSEL + row) * NWP + cb0 + w] = wtile[rr][w];
  }
}

// ---------------- 6. scan (1024 thr): ballot decision + urgent + 8-threads-per-word lazy OR ----------------
// wave 0: proven ballot/urgent decision. Lazy: word w owned by 8 subs; each loads
// <=2 mask words (klist padded x8) -> ONE latency batch; partials merge via LDS
// atomicOr (disjoint row subsets; schedule unchanged -> bit-identical results).
__global__ __launch_bounds__(1024, 1) void scan_kernel(const float4* __restrict__ boxes4,
                                                       const ull* __restrict__ mask,
                                                       const ull* __restrict__ diagT,
                                                       const ull* __restrict__ superT,
                                                       float4* __restrict__ out4) {
  __shared__ ull ldiagT[NBLK * 64];  // column form
  __shared__ ull lsuper[NBLK * 64];  // row form
  __shared__ ull S[96];
  __shared__ ull S_urg;
  __shared__ int klist[2][64];
  __shared__ int skeep[1024];
  __shared__ int s_kept, s_done, s_klen[2];
  int b = blockIdx.x;
  int tid = threadIdx.x;
  int lane = tid & 63;
  const ull* mb = mask + (size_t)b * KSEL * NWP;

  const ull* dt = diagT + (size_t)b * NBLK * 64;
  const ull* st = superT + (size_t)b * NBLK * 64;
  for (int i = tid; i < NBLK * 64; i += 1024) { ldiagT[i] = dt[i]; lsuper[i] = st[i]; }
  if (tid < 96) S[tid] = 0ull;
  if (tid == 0) { s_kept = 0; s_done = 0; s_klen[0] = 0; s_klen[1] = 0; S_urg = 0ull; }
  __syncthreads();

  for (int n = 0; n < NBLK; ++n) {
    if (tid < 64) {
      ull Sn = S[n] | S_urg;
      int i0 = n * 64;
      ull colT = ldiagT[i0 + lane];
      ull sd = (n + 1 < NBLK) ? lsuper[i0 + lane] : 0ull;
      int nval = KSEL - i0;
      ull valid = (nval >= 64) ? ~0ull : ((1ull << nval) - 1ull);
      ull A = ~Sn & valid;
      ull K = 0ull;
      int kept = s_kept;
      int done = 0;
      while (A) {
        int u = __builtin_ctzll(A);
        ++kept;
        K |= (1ull << u);
        if (kept >= PROP) { done = 1; break; }
        ull sup = __ballot(((colT >> u) & 1ull) != 0ull);
        A &= ~(sup | (1ull << u));
      }
      int klen = __builtin_popcountll(K);
      int kbase = kept - klen;
      if ((K >> lane) & 1ull) {
        int rank = __builtin_popcountll(K & ((1ull << lane) - 1ull));
        skeep[kbase + rank] = i0 + lane;
        klist[n & 1][rank] = i0 + lane;
      }
      int klp = (klen + 7) & ~7;     // pad to x8 with kept-row dup (idempotent)
      if (klen > 0 && lane >= klen && lane < klp)
        klist[n & 1][lane] = i0 + __builtin_ctzll(K);
      unsigned ulo = (unsigned)sd, uhi = (unsigned)(sd >> 32);
      if (!((K >> lane) & 1ull)) { ulo = 0u; uhi = 0u; }
#pragma unroll
      for (int m = 1; m < 64; m <<= 1) {
        ulo |= (unsigned)__shfl_xor((int)ulo, m, 64);
        uhi |= (unsigned)__shfl_xor((int)uhi, m, 64);
      }
      if (lane == 0) {
        s_klen[n & 1] = klen;
        S_urg = (ull)ulo | ((ull)uhi << 32);
        s_kept = kept;
        if (done || n == NBLK - 1) s_done = 1;
      }
    } else {
      // lazy: 8 subs per word; each sub loads klp8/8 words (usually 1-2, one batch)
      int prev = (n & 1) ^ 1;
      int kl = s_klen[prev];
      int lt = tid - 64;             // 0..959
      int wi = lt >> 3;              // 0..119
      int sub = lt & 7;
      int w = n + 1 + wi;
      if (kl > 0 && w < NB) {
        const int* kp = klist[prev];
        int klp8 = (kl + 7) & ~7;
        int per = klp8 >> 3;         // 1..8, block-uniform
        int base = sub * per;
        ull acc = 0ull;
#pragma unroll 8
        for (int ri = 0; ri < per; ++ri)
          acc |= mb[(size_t)kp[base + ri] * NWP + w];
        if (acc) atomicOr(&S[w], acc);
      }
    }
    __syncthreads();
    if (s_done) break;
  }

  int fin = s_kept;
  if (fin > PROP) fin = PROP;
  const float4* bx = boxes4 + (size_t)b * KSEL;
  for (int r2 = tid; r2 < PROP; r2 += 1024) {
    float4 v = make_float4(0.f, 0.f, 0.f, 0.f);
    if (r2 < fin) v = bx[skeep[r2]];
    out4[(size_t)b * PROP + r2] = v;
  }
}

// ---------------- launch (6 dispatches) ----------------
extern "C" void kernel_launch(void* const* d_in, const int* in_sizes, int n_in,
                              void* d_out, int out_size, void* d_ws, size_t ws_size,
                              hipStream_t stream) {
  const float4* probs4  = (const float4*)d_in[0];
  const float4* bbox4   = (const float4*)d_in[1];
  const float4* anchors4= (const float4*)d_in[2];
  float4* out4 = (float4*)d_out;
  char* ws = (char*)d_ws;

  int* cnt           = (int*)(ws + OFF_CNT);
  int* tsel          = (int*)(ws + OFF_TSEL);
  float4* boxes4     = (float4*)(ws + OFF_BOXES);
  ull* maskw         = (ull*)(ws + OFF_MASK);
  ull* diagT         = (ull*)(ws + OFF_DIAG);
  ull* superT        = (ull*)(ws + OFF_SUP);
  ull* keys          = (ull*)(ws + OFF_KEYS);
  unsigned int* hist = (unsigned int*)(ws + OFF_HIST);

  hipLaunchKernelGGL(hist_kernel,        dim3(HB, BATCH),      dim3(256),  0, stream, probs4, hist, cnt, keys);
  hipLaunchKernelGGL(thresh_kernel,      dim3(BATCH),          dim3(256),  0, stream, hist, tsel);
  hipLaunchKernelGGL(compact_kernel,     dim3(128, BATCH),     dim3(256),  0, stream, probs4, tsel, cnt, keys);
  hipLaunchKernelGGL(rankscatter_kernel, dim3(32, BATCH),      dim3(256),  0, stream, anchors4, bbox4, cnt, keys, boxes4);
  hipLaunchKernelGGL(mask_kernel,        dim3(24, NBLK2, BATCH), dim3(256), 0, stream, boxes4, maskw, diagT, superT);
  hipLaunchKernelGGL(scan_kernel,        dim3(BATCH),          dim3(1024), 0, stream, boxes4, maskw, diagT, superT, out4);
}

// Round 28
// 313.070 us; speedup vs baseline: 2.9319x; 1.0385x over previous
//
#include <hip/hip_runtime.h>
#include <hip/hip_bf16.h>

typedef unsigned long long ull;

// ---------------- problem constants ----------------
constexpr int BATCH = 8;
constexpr int NA    = 261888;
constexpr int KSEL  = 6000;          // PRE_NMS_LIMIT
constexpr int PROP  = 1000;          // PROPOSAL_COUNT
constexpr int CAP   = 8192;          // candidate capacity
constexpr int NBINS = 8192;          // histogram bins
constexpr int HB    = 16;            // private histogram blocks per batch
constexpr int NBLK  = 94;            // 64-row blocks (words)
constexpr int NBLK0 = 48;            // chunk0: blocks/words 0..47, rows 0..3071
constexpr int SPLIT = 3072;
constexpr int MC0_W = 48;            // words per row, chunk0 (words 0..47)
constexpr int MC1_W = 46;            // words per row, chunk1 (words 48..93)
constexpr int MC0_SZ = SPLIT * MC0_W;            // 147456 ull per batch
constexpr int MC1_SZ = (KSEL - SPLIT) * MC1_W;   // 134688 ull per batch
constexpr int MBATCH = MC0_SZ + MC1_SZ;          // 282144 ull per batch

// workspace layout (bytes). keys/hist alias the mask head (disjoint liveness).
constexpr size_t OFF_CNT   = 0;                       // 512 (128 ints)
constexpr size_t OFF_TSEL  = 512;                     // 32
constexpr size_t OFF_KC    = 544;                     // 64 (8 x {kept,done})
constexpr size_t OFF_BOXES = 608;                     // 8*6000*16 = 768000
constexpr size_t OFF_MASK  = 768608;                  // 8*282144*8 = 18,057,216
constexpr size_t OFF_DIAG  = OFF_MASK + 18057216;     // 385024
constexpr size_t OFF_SUP   = OFF_DIAG + 385024;       // 385024
constexpr size_t OFF_SKG   = OFF_SUP + 385024;        // 8*1024*4 = 32768
constexpr size_t OFF_GS    = OFF_SKG + 32768;         // 8*94*8 = 6016
constexpr size_t OFF_KEYS  = OFF_MASK;                // 524288 (aliased, dead pre-mask)
constexpr size_t OFF_HIST  = OFF_MASK + 2097152;      // 4MB (aliased, dead pre-mask)
// total ~19.6 MB (well under proven 37.65MB)

__device__ __forceinline__ int score_bin(float s) {
  int b = (int)(s * (float)NBINS);
  if (b < 0) b = 0;
  if (b > NBINS - 1) b = NBINS - 1;
  return b;
}

// ---------------- 1. histogram (+ init: cnt, keys pad, gS zero) ----------------
__global__ __launch_bounds__(256) void hist_kernel(const float4* __restrict__ probs4,
                                                   unsigned int* __restrict__ hist,
                                                   int* __restrict__ cnt,
                                                   ull* __restrict__ keys,
                                                   ull* __restrict__ gS) {
  __shared__ unsigned int lh[NBINS];
  for (int i = threadIdx.x; i < NBINS; i += 256) lh[i] = 0u;
  int fb = blockIdx.y * HB + blockIdx.x;   // 0..127
  if (threadIdx.x == 0) cnt[fb] = 0;
  {
    ull* kp = keys + (size_t)fb * 512;
    for (int i = threadIdx.x; i < 512; i += 256) kp[i] = ~0ull;
  }
  if (fb == 0) {
    for (int i = threadIdx.x; i < BATCH * NBLK; i += 256) gS[i] = 0ull;
  }
  __syncthreads();
  int b = blockIdx.y;
  const float4* p = probs4 + (size_t)b * (NA / 2);
  for (int a = blockIdx.x * 256 + threadIdx.x; a < NA / 2; a += HB * 256) {
    float4 v = p[a];
    atomicAdd(&lh[score_bin(v.y)], 1u);
    atomicAdd(&lh[score_bin(v.w)], 1u);
  }
  __syncthreads();
  unsigned int* gh = hist + ((size_t)b * HB + blockIdx.x) * NBINS;
  for (int i = threadIdx.x; i < NBINS; i += 256) gh[i] = lh[i];
}

// ---------------- 2. threshold bin select ----------------
__global__ __launch_bounds__(256) void thresh_kernel(const unsigned int* __restrict__ hist,
                                                     int* __restrict__ tsel) {
  constexpr int GR = NBINS / 256;
  __shared__ unsigned int ch[NBINS];
  __shared__ unsigned int gsum[256];
  int b = blockIdx.x;
  const unsigned int* h = hist + (size_t)b * HB * NBINS;
  for (int bin = threadIdx.x; bin < NBINS; bin += 256) {
    unsigned int s = 0;
    for (int k = 0; k < HB; ++k) s += h[(size_t)k * NBINS + bin];
    ch[bin] = s;
  }
  __syncthreads();
  unsigned int s = 0;
  int g0 = threadIdx.x * GR;
  for (int i = 0; i < GR; ++i) s += ch[g0 + i];
  gsum[threadIdx.x] = s;
  __syncthreads();
  if (threadIdx.x == 0) {
    unsigned int acc = 0;
    int g = 255;
    for (; g > 0; --g) {
      if (acc + gsum[g] >= (unsigned)KSEL) break;
      acc += gsum[g];
    }
    int t = g * GR;
    for (int bin = g * GR + GR - 1; bin >= g * GR; --bin) {
      acc += ch[bin];
      if (acc >= (unsigned)KSEL) { t = bin; break; }
    }
    tsel[b] = t;
  }
}

// ---------------- 3. compact candidates (float4 loads) ----------------
__global__ __launch_bounds__(256) void compact_kernel(const float4* __restrict__ probs4,
                                                      const int* __restrict__ tsel,
                                                      int* __restrict__ cnt,
                                                      ull* __restrict__ keys) {
  __shared__ int lcnt, lbase;
  __shared__ ull lbuf[2048];
  int b = blockIdx.y;
  int t = tsel[b];
  if (threadIdx.x == 0) lcnt = 0;
  __syncthreads();
  const float4* p = probs4 + (size_t)b * (NA / 2);
  for (int a = blockIdx.x * blockDim.x + threadIdx.x; a < NA / 2; a += gridDim.x * blockDim.x) {
    float4 v = p[a];
    if (score_bin(v.y) >= t) {
      int pos = atomicAdd(&lcnt, 1);
      unsigned int ib = ~__float_as_uint(v.y);
      lbuf[pos] = ((ull)ib << 32) | (unsigned int)(2 * a);
    }
    if (score_bin(v.w) >= t) {
      int pos = atomicAdd(&lcnt, 1);
      unsigned int ib = ~__float_as_uint(v.w);
      lbuf[pos] = ((ull)ib << 32) | (unsigned int)(2 * a + 1);
    }
  }
  __syncthreads();
  if (threadIdx.x == 0) lbase = atomicAdd(&cnt[b * 16], lcnt);
  __syncthreads();
  int n = lcnt, base = lbase;
  ull* kb = keys + (size_t)b * CAP;
  for (int i = threadIdx.x; i < n; i += 256) {
    int pos = base + i;
    if (pos < CAP) kb[pos] = lbuf[i];
  }
}

// ---------------- 4. fused rank+scatter, LDS-tiled key stream ----------------
__global__ __launch_bounds__(256) void rankscatter_kernel(const float4* __restrict__ anchors4,
                                                          const float4* __restrict__ bbox4,
                                                          const int* __restrict__ cnt,
                                                          const ull* __restrict__ keys,
                                                          float4* __restrict__ boxes4) {
#pragma clang fp contract(off)
  __shared__ ull tile[1024];
  int b = blockIdx.y;
  int n = cnt[b * 16];
  if (n > CAP) n = CAP;
  int i = blockIdx.x * 256 + threadIdx.x;
  const ull* kb = keys + (size_t)b * CAP;
  ull my = (i < CAP) ? kb[(i < n) ? i : 0] : ~0ull;
  if (i >= n) my = ~0ull;
  unsigned int r = 0;
  int ntile = (n + 1023) & ~1023;
  for (int j0 = 0; j0 < ntile; j0 += 1024) {
    for (int k = threadIdx.x; k < 1024; k += 256) tile[k] = kb[j0 + k];
    __syncthreads();
#pragma unroll 16
    for (int k = 0; k < 1024; ++k) r += (tile[k] < my) ? 1u : 0u;
    __syncthreads();
  }
  if (i >= n || r >= (unsigned)KSEL) return;
  int a = (int)(unsigned int)(my & 0xffffffffull);
  float4 anc = anchors4[(size_t)b * NA + a];
  float4 d   = bbox4[(size_t)b * NA + a];
  float h = anc.z - anc.x;
  float w = anc.w - anc.y;
  float dy = d.x * 0.1f, dx = d.y * 0.1f, dh = d.z * 0.2f, dw = d.w * 0.2f;
  float cy = (anc.x + (0.5f * h)) + (dy * h);
  float cx = (anc.y + (0.5f * w)) + (dx * w);
  float h2 = h * expf(dh);
  float w2 = w * expf(dw);
  float y1 = cy - 0.5f * h2;
  float x1 = cx - 0.5f * w2;
  float y2 = y1 + h2;
  float x2 = x1 + w2;
  y1 = fminf(fmaxf(y1, 0.f), 1.f);
  x1 = fminf(fmaxf(x1, 0.f), 1.f);
  y2 = fminf(fmaxf(y2, 0.f), 1.f);
  x2 = fminf(fmaxf(x2, 0.f), 1.f);
  boxes4[(size_t)b * KSEL + r] = make_float4(y1, x1, y2, x2);
}

// ---------------- 5. suppression mask (proven 2-row structure, parameterized chunks) ----------------
// chunk c0: rb2 0..23, words w0..47, packed stride 48. chunk c1: rb2 24..46, words w0..93,
// packed stride 46 (stored w-48). diagT col-form via ballot transpose; superT row-form.
__global__ __launch_bounds__(256) void mask_kernel(const float4* __restrict__ boxes4,
                                                   ull* __restrict__ maskw,
                                                   ull* __restrict__ diagT,
                                                   ull* __restrict__ superT,
                                                   int rb2Base, int rowBase, int wordBase,
                                                   int wordLim, int stride, int chunkOff) {
#pragma clang fp contract(off)
  int cx = blockIdx.x, b = blockIdx.z;
  int rb2 = rb2Base + blockIdx.y;
  int w0 = 2 * rb2;
  int cb0 = w0 + 4 * cx;
  if (cb0 >= wordLim) return;
  __shared__ float4 colbox[4][64];
  __shared__ float  colca[4][64];
  __shared__ ull wtile[128][5];
  int tid = threadIdx.x, wv = tid >> 6, l = tid & 63;
  int cb = cb0 + wv;
  int rA = rb2 * 128 + l, rB = rA + 64;
  float4 zero = make_float4(0.f, 0.f, 0.f, 0.f);
  float4 boxA = (rA < KSEL) ? boxes4[(size_t)b * KSEL + rA] : zero;
  float4 boxB = (rB < KSEL) ? boxes4[(size_t)b * KSEL + rB] : zero;
  float areaA = (boxA.z - boxA.x) * (boxA.w - boxA.y);
  float areaB = (boxB.z - boxB.x) * (boxB.w - boxB.y);
  int c = cb * 64 + l;
  float4 cload = (cb < wordLim && c < KSEL) ? boxes4[(size_t)b * KSEL + c] : zero;
  colbox[wv][l] = cload;
  colca[wv][l] = (cload.z - cload.x) * (cload.w - cload.y);
  __syncthreads();
  ull bitsA = 0ull, bitsB = 0ull;
  if (cb < wordLim) {
#pragma unroll
    for (int u = 0; u < 64; ++u) {
      float4 cbx = colbox[wv][u];
      float ca = colca[wv][u];
      {
        float ih = fmaxf(fminf(boxA.z, cbx.z) - fmaxf(boxA.x, cbx.x), 0.f);
        float iw = fmaxf(fminf(boxA.w, cbx.w) - fmaxf(boxA.y, cbx.y), 0.f);
        float inter = ih * iw;
        float uni = (areaA + ca) - inter;
        float d = fmaf(-0.7f, uni, inter);
        float tt = 6e-7f * uni;
        bool keep;
        if (__builtin_fabsf(d) <= tt) keep = (inter / uni) > 0.7f;
        else keep = d > 0.f;
        if (keep) bitsA |= (1ull << u);
      }
      {
        float ih = fmaxf(fminf(boxB.z, cbx.z) - fmaxf(boxB.x, cbx.x), 0.f);
        float iw = fmaxf(fminf(boxB.w, cbx.w) - fmaxf(boxB.y, cbx.y), 0.f);
        float inter = ih * iw;
        float uni = (areaB + ca) - inter;
        float d = fmaf(-0.7f, uni, inter);
        float tt = 6e-7f * uni;
        bool keep;
        if (__builtin_fabsf(d) <= tt) keep = (inter / uni) > 0.7f;
        else keep = d > 0.f;
        if (keep) bitsB |= (1ull << u);
      }
    }
    if (cb == w0) {
      bitsA &= (l == 63) ? 0ull : (~0ull << (l + 1)); // only cc > row suppress
      ull colT = 0ull;
#pragma unroll
      for (int k = 0; k < 64; ++k) {
        ull bk = __ballot(((bitsA >> k) & 1ull) != 0ull);
        if (l == k) colT = bk;
      }
      diagT[((size_t)b * NBLK + w0) * 64 + l] = colT;
    }
    if (cb == w0 + 1) {
      superT[((size_t)b * NBLK + w0) * 64 + l] = bitsA;  // word w0+1 of block-w0 rows
      bitsB &= (l == 63) ? 0ull : (~0ull << (l + 1));
      ull colT = 0ull;
#pragma unroll
      for (int k = 0; k < 64; ++k) {
        ull bk = __ballot(((bitsB >> k) & 1ull) != 0ull);
        if (l == k) colT = bk;
      }
      diagT[((size_t)b * NBLK + w0 + 1) * 64 + l] = colT;
    }
    if (cb == w0 + 2) {
      superT[((size_t)b * NBLK + w0 + 1) * 64 + l] = bitsB;
    }
  }
  wtile[l][wv] = bitsA;
  wtile[l + 64][wv] = bitsB;
  __syncthreads();
  int base_row = rb2 * 128;
#pragma unroll
  for (int pass = 0; pass < 2; ++pass) {
    int idx = pass * 256 + tid;
    int rr = idx >> 2, w = idx & 3;
    int row = base_row + rr;
    int cw = cb0 + w;
    if (row < KSEL && cw < wordLim)
      maskw[(size_t)b * MBATCH + chunkOff + (size_t)(row - rowBase) * stride + (cw - wordBase)]
        = wtile[rr][w];
  }
}

// ---------------- 5b. cross-chunk mask: kept chunk0 rows x words 48..93 -> gS ----------------
__global__ __launch_bounds__(64) void maskx_kernel(const float4* __restrict__ boxes4,
                                                   const int* __restrict__ skeepG,
                                                   const int* __restrict__ kc,
                                                   ull* __restrict__ gS) {
#pragma clang fp contract(off)
  __shared__ float4 colbox[64];
  __shared__ float  colca[64];
  int b = blockIdx.z;
  int kept0 = kc[b * 2];
  int rg = blockIdx.y;
  if (rg * 64 >= kept0) return;
  int l = threadIdx.x;
  int w = NBLK0 + blockIdx.x;      // word 48..93
  int c = w * 64 + l;
  float4 zero = make_float4(0.f, 0.f, 0.f, 0.f);
  float4 cld = (c < KSEL) ? boxes4[(size_t)b * KSEL + c] : zero;
  colbox[l] = cld;
  colca[l] = (cld.z - cld.x) * (cld.w - cld.y);
  __syncthreads();
  int idx = rg * 64 + l;
  ull bits = 0ull;
  if (idx < kept0) {
    int r = skeepG[b * 1024 + idx];
    float4 rb = boxes4[(size_t)b * KSEL + r];
    float rA = (rb.z - rb.x) * (rb.w - rb.y);
#pragma unroll
    for (int u = 0; u < 64; ++u) {
      float4 cbx = colbox[u];
      float ca = colca[u];
      float ih = fmaxf(fminf(rb.z, cbx.z) - fmaxf(rb.x, cbx.x), 0.f);
      float iw = fmaxf(fminf(rb.w, cbx.w) - fmaxf(rb.y, cbx.y), 0.f);
      float inter = ih * iw;
      float uni = (rA + ca) - inter;
      float d = fmaf(-0.7f, uni, inter);
      float tt = 6e-7f * uni;
      bool keep;
      if (__builtin_fabsf(d) <= tt) keep = (inter / uni) > 0.7f;
      else keep = d > 0.f;
      if (keep) bits |= (1ull << u);
    }
  }
  unsigned lo = (unsigned)bits, hi = (unsigned)(bits >> 32);
#pragma unroll
  for (int m = 1; m < 64; m <<= 1) {
    lo |= (unsigned)__shfl_xor((int)lo, m, 64);
    hi |= (unsigned)__shfl_xor((int)hi, m, 64);
  }
  if (l == 0) {
    ull v = (ull)lo | ((ull)hi << 32);
    if (v) atomicOr(&gS[b * NBLK + w], v);
  }
}

// ---------------- 6. scan (two phases): ballot decision + urgent + 8-sub lazy OR ----------------
template<int PHASE>
__global__ __launch_bounds__(1024, 1) void scan_kernel(const float4* __restrict__ boxes4,
                                                       const ull* __restrict__ maskw,
                                                       const ull* __restrict__ diagT,
                                                       const ull* __restrict__ superT,
                                                       int* __restrict__ skeepG,
                                                       int* __restrict__ kc,
                                                       const ull* __restrict__ gS,
                                                       float4* __restrict__ out4) {
  __shared__ ull ldiagT[NBLK * 64];
  __shared__ ull lsuper[NBLK * 64];
  __shared__ ull S[96];
  __shared__ ull S_urg;
  __shared__ int klist[2][64];
  __shared__ int skeep[1024];
  __shared__ int s_kept, s_done, s_klen[2];
  int b = blockIdx.x;
  int tid = threadIdx.x;
  int lane = tid & 63;
  const ull* mb = maskw + (size_t)b * MBATCH;
  const int nB = PHASE ? NBLK0 : 0;
  const int nE = PHASE ? NBLK : NBLK0;

  const ull* dt = diagT + (size_t)b * NBLK * 64;
  const ull* st = superT + (size_t)b * NBLK * 64;
  for (int i = nB * 64 + tid; i < nE * 64; i += 1024) { ldiagT[i] = dt[i]; lsuper[i] = st[i]; }
  if (PHASE == 0) {
    if (tid < 96) S[tid] = 0ull;
    if (tid == 0) { s_kept = 0; s_done = 0; s_klen[0] = 0; s_klen[1] = 0; S_urg = 0ull; }
  } else {
    int k0 = kc[b * 2], d0 = kc[b * 2 + 1];
    if (tid < 96) S[tid] = (tid >= NBLK0 && tid < NBLK) ? gS[b * NBLK + tid] : 0ull;
    for (int i = tid; i < k0; i += 1024) skeep[i] = skeepG[b * 1024 + i];
    if (tid == 0) { s_kept = k0; s_done = d0; s_klen[0] = 0; s_klen[1] = 0; S_urg = 0ull; }
  }
  __syncthreads();

  for (int n = nB; n < nE; ++n) {
    if (s_done) break;
    if (tid < 64) {
      ull Sn = S[n] | S_urg;
      int i0 = n * 64;
      ull colT = ldiagT[i0 + lane];
      ull sd = (n + 1 < NBLK) ? lsuper[i0 + lane] : 0ull;
      int nval = KSEL - i0;
      ull valid = (nval >= 64) ? ~0ull : ((1ull << nval) - 1ull);
      ull A = ~Sn & valid;
      ull K = 0ull;
      int kept = s_kept;
      int done = 0;
      while (A) {
        int u = __builtin_ctzll(A);
        ++kept;
        K |= (1ull << u);
        if (kept >= PROP) { done = 1; break; }
        ull sup = __ballot(((colT >> u) & 1ull) != 0ull);
        A &= ~(sup | (1ull << u));
      }
      int klen = __builtin_popcountll(K);
      int kbase = kept - klen;
      if ((K >> lane) & 1ull) {
        int rank = __builtin_popcountll(K & ((1ull << lane) - 1ull));
        skeep[kbase + rank] = i0 + lane;
        klist[n & 1][rank] = i0 + lane;
      }
      int klp = (klen + 7) & ~7;
      if (klen > 0 && lane >= klen && lane < klp)
        klist[n & 1][lane] = i0 + __builtin_ctzll(K);
      unsigned ulo = (unsigned)sd, uhi = (unsigned)(sd >> 32);
      if (!((K >> lane) & 1ull)) { ulo = 0u; uhi = 0u; }
#pragma unroll
      for (int m = 1; m < 64; m <<= 1) {
        ulo |= (unsigned)__shfl_xor((int)ulo, m, 64);
        uhi |= (unsigned)__shfl_xor((int)uhi, m, 64);
      }
      if (lane == 0) {
        s_klen[n & 1] = klen;
        S_urg = (ull)ulo | ((ull)uhi << 32);
        s_kept = kept;
        if (done) s_done = 1;
      }
    } else {
      int prev = (n & 1) ^ 1;
      int kl = s_klen[prev];
      int lt = tid - 64;
      int wi = lt >> 3;
      int sub = lt & 7;
      int w = n + 1 + wi;
      if (kl > 0 && w < nE) {
        const int* kp = klist[prev];
        int klp8 = (kl + 7) & ~7;
        int per = klp8 >> 3;
        int base = sub * per;
        ull acc = 0ull;
#pragma unroll 8
        for (int ri = 0; ri < per; ++ri) {
          int r = kp[base + ri];
          size_t addr = (PHASE == 0) ? ((size_t)r * MC0_W + w)
                                     : ((size_t)MC0_SZ + (size_t)(r - SPLIT) * MC1_W + (w - NBLK0));
          acc |= mb[addr];
        }
        if (acc) atomicOr(&S[w], acc);
      }
    }
    __syncthreads();
  }

  if (PHASE == 0) {
    int k0 = s_kept;
    if (k0 > PROP) k0 = PROP;
    for (int i = tid; i < k0; i += 1024) skeepG[b * 1024 + i] = skeep[i];
    if (tid == 0) { kc[b * 2] = k0; kc[b * 2 + 1] = s_done; }
  } else {
    int fin = s_kept;
    if (fin > PROP) fin = PROP;
    const float4* bx = boxes4 + (size_t)b * KSEL;
    for (int r2 = tid; r2 < PROP; r2 += 1024) {
      float4 v = make_float4(0.f, 0.f, 0.f, 0.f);
      if (r2 < fin) v = bx[skeep[r2]];
      out4[(size_t)b * PROP + r2] = v;
    }
  }
}

// ---------------- launch (9 dispatches) ----------------
extern "C" void kernel_launch(void* const* d_in, const int* in_sizes, int n_in,
                              void* d_out, int out_size, void* d_ws, size_t ws_size,
                              hipStream_t stream) {
  const float4* probs4  = (const float4*)d_in[0];
  const float4* bbox4   = (const float4*)d_in[1];
  const float4* anchors4= (const float4*)d_in[2];
  float4* out4 = (float4*)d_out;
  char* ws = (char*)d_ws;

  int* cnt           = (int*)(ws + OFF_CNT);
  int* tsel          = (int*)(ws + OFF_TSEL);
  int* kc            = (int*)(ws + OFF_KC);
  float4* boxes4     = (float4*)(ws + OFF_BOXES);
  ull* maskw         = (ull*)(ws + OFF_MASK);
  ull* diagT         = (ull*)(ws + OFF_DIAG);
  ull* superT        = (ull*)(ws + OFF_SUP);
  int* skeepG        = (int*)(ws + OFF_SKG);
  ull* gS            = (ull*)(ws + OFF_GS);
  ull* keys          = (ull*)(ws + OFF_KEYS);
  unsigned int* hist = (unsigned int*)(ws + OFF_HIST);

  hipLaunchKernelGGL(hist_kernel,        dim3(HB, BATCH),    dim3(256), 0, stream, probs4, hist, cnt, keys, gS);
  hipLaunchKernelGGL(thresh_kernel,      dim3(BATCH),        dim3(256), 0, stream, hist, tsel);
  hipLaunchKernelGGL(compact_kernel,     dim3(128, BATCH),   dim3(256), 0, stream, probs4, tsel, cnt, keys);
  hipLaunchKernelGGL(rankscatter_kernel, dim3(32, BATCH),    dim3(256), 0, stream, anchors4, bbox4, cnt, keys, boxes4);
  // chunk0 mask: rows 0..3071, words 0..47
  hipLaunchKernelGGL(mask_kernel, dim3(12, 24, BATCH), dim3(256), 0, stream,
                     boxes4, maskw, diagT, superT, 0, 0, 0, NBLK0, MC0_W, 0);
  // chunk1 mask: rows 3072..5999, words 48..93
  hipLaunchKernelGGL(mask_kernel, dim3(12, 23, BATCH), dim3(256), 0, stream,
                     boxes4, maskw, diagT, superT, 24, SPLIT, NBLK0, NBLK, MC1_W, MC0_SZ);
  scan_kernel<0><<<dim3(BATCH), dim3(1024), 0, stream>>>(boxes4, maskw, diagT, superT,
                                                         skeepG, kc, gS, out4);
  hipLaunchKernelGGL(maskx_kernel, dim3(NBLK - NBLK0, 16, BATCH), dim3(64), 0, stream,
                     boxes4, skeepG, kc, gS);
  scan_kernel<1><<<dim3(BATCH), dim3(1024), 0, stream>>>(boxes4, maskw, diagT, superT,
                                                         skeepG, kc, gS, out4);
}